// Round 5
// baseline (1431.066 us; speedup 1.0000x reference)
//
#include <hip/hip_runtime.h>
#include <hip/hip_bf16.h>
#include <cstdint>
#include <cstddef>

using bf16 = __hip_bfloat16;
typedef __bf16 bf16x8 __attribute__((ext_vector_type(8)));
typedef unsigned short u16x8 __attribute__((ext_vector_type(8)));
typedef float f32x4 __attribute__((ext_vector_type(4)));

__device__ __forceinline__ float bf2f(unsigned short u) {
    union { unsigned int i; float f; } c; c.i = ((unsigned int)u) << 16; return c.f;
}
__device__ __forceinline__ unsigned short f2bf(float f) {
    union { float f; unsigned int i; } c; c.f = f;
    unsigned int r = c.i + 0x7FFFu + ((c.i >> 16) & 1u);
    return (unsigned short)(r >> 16);
}
__device__ __forceinline__ bf16x8 as_bf(u16x8 u) {
    union { u16x8 u; bf16x8 b; } c; c.u = u; return c.b;
}

#define AS1 __attribute__((address_space(1)))
#define AS3 __attribute__((address_space(3)))
__device__ __forceinline__ void gload_lds16(const void* g, void* l) {
    __builtin_amdgcn_global_load_lds((const AS1 void*)g, (AS3 void*)l, 16, 0, 0);
}

// ---------------- fp32 -> bf16 convert (8 elems/thread) -------------------
__global__ __launch_bounds__(256)
void cvt_f32_bf16(const float* __restrict__ in, bf16* __restrict__ out, int n)
{
    const int i = (blockIdx.x * 256 + threadIdx.x) * 8;
    if (i >= n) return;
    float4 a = *(const float4*)(in + i);
    float4 b = *(const float4*)(in + i + 4);
    u16x8 o;
    o[0] = f2bf(a.x); o[1] = f2bf(a.y); o[2] = f2bf(a.z); o[3] = f2bf(a.w);
    o[4] = f2bf(b.x); o[5] = f2bf(b.y); o[6] = f2bf(b.z); o[7] = f2bf(b.w);
    *(u16x8*)((unsigned short*)out + i) = o;
}

// -------- weight transpose + convert: in[K][N] fp32 -> out[N][K] bf16 -----
__global__ __launch_bounds__(256)
void transpose_w(const float* __restrict__ in, bf16* __restrict__ out, int K, int N)
{
    __shared__ unsigned short t[32][33];
    const int nt = N >> 5;
    const int bx = blockIdx.x % nt, by = blockIdx.x / nt;
    const int tx = threadIdx.x & 31, ty = threadIdx.x >> 5;   // ty 0..7
    unsigned short* outu = (unsigned short*)out;
#pragma unroll
    for (int i = 0; i < 32; i += 8)
        t[ty + i][tx] = f2bf(in[(size_t)(by * 32 + ty + i) * N + bx * 32 + tx]);
    __syncthreads();
#pragma unroll
    for (int i = 0; i < 32; i += 8)
        outu[(size_t)(bx * 32 + ty + i) * K + by * 32 + tx] = t[tx][ty + i];
}

// ---------------- GEMM: C[M,N] = A[M,K] @ Bt[N,K]^T + bias, opt ReLU ------
// 128x128 tile, BK=32, 256 threads = 4 waves (2x2), each wave 64x64 out.
// A, Bt bf16; bias fp32; C bf16.  (m97-pattern)
template<bool RELU>
__global__ __launch_bounds__(256)
void gemm_bt(const bf16* __restrict__ A, const bf16* __restrict__ Bt,
             const float* __restrict__ bias, bf16* __restrict__ C,
             int M, int N, int K)
{
    __shared__ unsigned short lA[128 * 32];
    __shared__ unsigned short lB[128 * 32];
    const int tid = threadIdx.x;
    const int lane = tid & 63, wid = tid >> 6;
    const int ntiles = N >> 7;
    const int bx = blockIdx.x % ntiles, by = blockIdx.x / ntiles;
    const long tm = (long)by << 7, tn = (long)bx << 7;

    const int wr = wid >> 1, wc = wid & 1;
    const int lrow = lane & 15, lk8 = (lane >> 4) << 3;

    f32x4 acc[4][4] = {};

    const int srow = wid * 16 + (lane >> 2);
    const int scol = (lane & 3) << 3;
    const bf16* gA0 = A + (tm + srow) * (long)K + scol;
    const bf16* gB0 = Bt + (tn + srow) * (long)K + scol;
    unsigned short* lA0 = lA + (wid * 16) * 32;
    unsigned short* lB0 = lB + (wid * 16) * 32;

    for (int kt = 0; kt < K; kt += 32) {
        gload_lds16(gA0 + kt,                lA0);
        gload_lds16(gA0 + 64 * (long)K + kt, lA0 + 64 * 32);
        gload_lds16(gB0 + kt,                lB0);
        gload_lds16(gB0 + 64 * (long)K + kt, lB0 + 64 * 32);
        __syncthreads();

        bf16x8 af[4], bfv[4];
#pragma unroll
        for (int m = 0; m < 4; ++m)
            af[m] = as_bf(*(const u16x8*)(lA + (wr * 64 + m * 16 + lrow) * 32 + lk8));
#pragma unroll
        for (int n = 0; n < 4; ++n)
            bfv[n] = as_bf(*(const u16x8*)(lB + (wc * 64 + n * 16 + lrow) * 32 + lk8));
#pragma unroll
        for (int m = 0; m < 4; ++m)
#pragma unroll
            for (int n = 0; n < 4; ++n)
                acc[m][n] = __builtin_amdgcn_mfma_f32_16x16x32_bf16(af[m], bfv[n], acc[m][n], 0, 0, 0);
        __syncthreads();
    }

    unsigned short* Cu = (unsigned short*)C;
#pragma unroll
    for (int n = 0; n < 4; ++n) {
        const long gc = tn + wc * 64 + n * 16 + lrow;
        const float bv = bias[gc];
#pragma unroll
        for (int m = 0; m < 4; ++m) {
            const long gr0 = tm + wr * 64 + m * 16 + ((lane >> 4) << 2);
#pragma unroll
            for (int j = 0; j < 4; ++j) {
                float v = acc[m][n][j] + bv;
                if (RELU) v = fmaxf(v, 0.f);
                Cu[(gr0 + j) * (long)N + gc] = f2bf(v);
            }
        }
    }
}

// ---------------- simple VALU flash attention (layout-assumption-free) ----
// grid (S/64, B*H); 256 threads. Thread (r = tid>>2, c = tid&3) owns q-row r
// and key-quarter / hd-quarter c. All data f32 in LDS, explicit indexing.
__global__ __launch_bounds__(256)
void attn_simple(const bf16* __restrict__ Qb, const bf16* __restrict__ Kb,
                 const bf16* __restrict__ Vb, bf16* __restrict__ Ob,
                 int qRS, int kRS, int qHS, int kHS)
{
    __shared__ float lQ[64][68];
    __shared__ float lK[64][68];
    __shared__ float lV[64][68];
    __shared__ float lP[64][68];

    const int tid = threadIdx.x;
    const int r = tid >> 2;        // q-row within block, 0..63
    const int c = tid & 3;         // quarter, 0..3 (same wave as r's other threads)
    const int bh = blockIdx.y, b = bh >> 3, h = bh & 7;
    const int q0 = blockIdx.x * 64;

    const unsigned short* Q = (const unsigned short*)Qb + (size_t)b * 2048 * qRS + (size_t)h * qHS;
    const unsigned short* K = (const unsigned short*)Kb + (size_t)b * 2048 * kRS + (size_t)h * kHS;
    const unsigned short* V = (const unsigned short*)Vb + (size_t)b * 2048 * kRS + (size_t)h * kHS;
    unsigned short* O = (unsigned short*)Ob + (size_t)b * 2048 * 512 + (size_t)h * 64;

    const int sr = tid >> 3, sc8 = (tid & 7) << 3;   // staging: 32 rows x 64 cols/pass

    // stage Q once, scaled by 1/sqrt(64)
#pragma unroll
    for (int half = 0; half < 64; half += 32) {
        u16x8 q8 = *(const u16x8*)(Q + (size_t)(q0 + sr + half) * qRS + sc8);
#pragma unroll
        for (int j = 0; j < 8; ++j) lQ[sr + half][sc8 + j] = bf2f(q8[j]) * 0.125f;
    }
    __syncthreads();

    float m = -1e30f, lsum = 0.f;
    float o[16];
#pragma unroll
    for (int d = 0; d < 16; ++d) o[d] = 0.f;

    for (int kt = 0; kt < 2048; kt += 64) {
#pragma unroll
        for (int half = 0; half < 64; half += 32) {
            u16x8 k8 = *(const u16x8*)(K + (size_t)(kt + sr + half) * kRS + sc8);
            u16x8 v8 = *(const u16x8*)(V + (size_t)(kt + sr + half) * kRS + sc8);
#pragma unroll
            for (int j = 0; j < 8; ++j) {
                lK[sr + half][sc8 + j] = bf2f(k8[j]);
                lV[sr + half][sc8 + j] = bf2f(v8[j]);
            }
        }
        __syncthreads();

        // scores for this thread's 16 keys
        float s[16];
#pragma unroll
        for (int kk = 0; kk < 16; ++kk) {
            const int key = c * 16 + kk;
            float acc = 0.f;
#pragma unroll
            for (int d = 0; d < 64; ++d) acc += lQ[r][d] * lK[key][d];
            s[kk] = acc;
        }
        float tmax = s[0];
#pragma unroll
        for (int kk = 1; kk < 16; ++kk) tmax = fmaxf(tmax, s[kk]);
        tmax = fmaxf(tmax, __shfl_xor(tmax, 1));
        tmax = fmaxf(tmax, __shfl_xor(tmax, 2));
        const float nm = fmaxf(m, tmax);
        const float corr = expf(m - nm);
        m = nm;
        float rs = 0.f;
#pragma unroll
        for (int kk = 0; kk < 16; ++kk) {
            float p = expf(s[kk] - nm);
            lP[r][c * 16 + kk] = p;
            rs += p;
        }
        rs += __shfl_xor(rs, 1);
        rs += __shfl_xor(rs, 2);
        lsum = lsum * corr + rs;
#pragma unroll
        for (int d = 0; d < 16; ++d) o[d] *= corr;

        // lP row r written by the 4 same-wave threads (r,*): fence LDS ops
        asm volatile("s_waitcnt lgkmcnt(0)" ::: "memory");
        __builtin_amdgcn_sched_barrier(0);

        // PV: o[d] += sum_key P[r][key] * V[key][c*16+d]
        for (int key = 0; key < 64; ++key) {
            const float p = lP[r][key];
#pragma unroll
            for (int d = 0; d < 16; ++d) o[d] += p * lV[key][c * 16 + d];
        }
        __syncthreads();   // WAR: before next tile's lK/lV/lP overwrite
    }

    const float inv = 1.f / lsum;
#pragma unroll
    for (int d = 0; d < 16; ++d)
        O[(size_t)(q0 + r) * 512 + c * 16 + d] = f2bf(o[d] * inv);
}

// ------- fused residual + LayerNorm (Bessel, eps on std), fp32 residual ---
// a: bf16 (gemm out); r: fp32 residual; writes fp32 residual-out and
// (optionally) bf16 activation for the next GEMM.
template<bool WRITE_BF>
__global__ __launch_bounds__(64)
void ln_residual(const bf16* __restrict__ a, const float* __restrict__ r,
                 const float* __restrict__ g, const float* __restrict__ bparm,
                 bf16* __restrict__ out_bf, float* __restrict__ out_f32)
{
    const int row = blockIdx.x, lane = threadIdx.x;
    const size_t base = (size_t)row * 512 + lane * 8;
    u16x8 av = *(const u16x8*)((const unsigned short*)a + base);
    float4 rv0 = *(const float4*)(r + base);
    float4 rv1 = *(const float4*)(r + base + 4);
    const float rr[8] = {rv0.x, rv0.y, rv0.z, rv0.w, rv1.x, rv1.y, rv1.z, rv1.w};
    float x[8]; float s = 0.f, ss = 0.f;
#pragma unroll
    for (int j = 0; j < 8; ++j) {
        x[j] = bf2f(av[j]) + rr[j];
        s += x[j]; ss += x[j] * x[j];
    }
#pragma unroll
    for (int off = 32; off > 0; off >>= 1) {
        s += __shfl_xor(s, off);
        ss += __shfl_xor(ss, off);
    }
    const float mean = s * (1.f / 512.f);
    float var = (ss - 512.f * mean * mean) * (1.f / 511.f);
    var = fmaxf(var, 0.f);
    const float inv = 1.f / (sqrtf(var) + 1e-5f);
    float4 gv0 = *(const float4*)(g + lane * 8);
    float4 gv1 = *(const float4*)(g + lane * 8 + 4);
    float4 bv0 = *(const float4*)(bparm + lane * 8);
    float4 bv1 = *(const float4*)(bparm + lane * 8 + 4);
    const float gg[8] = {gv0.x, gv0.y, gv0.z, gv0.w, gv1.x, gv1.y, gv1.z, gv1.w};
    const float bb[8] = {bv0.x, bv0.y, bv0.z, bv0.w, bv1.x, bv1.y, bv1.z, bv1.w};
    float ov[8];
#pragma unroll
    for (int j = 0; j < 8; ++j)
        ov[j] = gg[j] * (x[j] - mean) * inv + bb[j];
    float4 w0 = {ov[0], ov[1], ov[2], ov[3]};
    float4 w1 = {ov[4], ov[5], ov[6], ov[7]};
    *(float4*)(out_f32 + base) = w0;
    *(float4*)(out_f32 + base + 4) = w1;
    if constexpr (WRITE_BF) {
        u16x8 ob;
#pragma unroll
        for (int j = 0; j < 8; ++j) ob[j] = f2bf(ov[j]);
        *(u16x8*)((unsigned short*)out_bf + base) = ob;
    }
}

// ---------------- launch --------------------------------------------------
extern "C" void kernel_launch(void* const* d_in, const int* in_sizes, int n_in,
                              void* d_out, int out_size, void* d_ws, size_t ws_size,
                              hipStream_t stream)
{
    (void)in_sizes; (void)n_in; (void)out_size;
    const float* x          = (const float*)d_in[0];
    const float* y          = (const float*)d_in[1];
    const float* qkv_w      = (const float*)d_in[4];
    const float* qkv_b      = (const float*)d_in[5];
    const float* self_out_w = (const float*)d_in[6];
    const float* self_out_b = (const float*)d_in[7];
    const float* kv_w       = (const float*)d_in[8];
    const float* kv_b       = (const float*)d_in[9];
    const float* q_w        = (const float*)d_in[10];
    const float* q_b        = (const float*)d_in[11];
    const float* cross_out_w= (const float*)d_in[12];
    const float* cross_out_b= (const float*)d_in[13];
    const float* ffn_w1     = (const float*)d_in[14];
    const float* ffn_b1     = (const float*)d_in[15];
    const float* ffn_w2     = (const float*)d_in[16];
    const float* ffn_b2     = (const float*)d_in[17];
    const float* g1 = (const float*)d_in[18];
    const float* b1 = (const float*)d_in[19];
    const float* g2 = (const float*)d_in[20];
    const float* b2 = (const float*)d_in[21];
    const float* g3 = (const float*)d_in[22];
    const float* b3 = (const float*)d_in[23];

    bf16* w = (bf16*)d_ws;
    size_t off = 0;
    auto take = [&](size_t n) { bf16* p = w + off; off += n; return p; };
    bf16* qkv_wT   = take((size_t)1536 * 512);
    bf16* self_wT  = take((size_t)512 * 512);
    bf16* kv_wT    = take((size_t)1024 * 512);
    bf16* q_wT     = take((size_t)512 * 512);
    bf16* cross_wT = take((size_t)512 * 512);
    bf16* ffn1_wT  = take((size_t)2048 * 512);
    bf16* ffn2_wT  = take((size_t)512 * 2048);
    bf16* x_bf  = take((size_t)4096 * 512);     // R2 overlays x_bf+y_bf later
    bf16* y_bf  = take((size_t)4096 * 512);
    bf16* bufA  = take((size_t)4096 * 2048);    // qkv out / kv+q out / ffn1 out
    bf16* bufB  = take((size_t)4096 * 512);     // attn out / ffn2 out
    bf16* bufC  = take((size_t)4096 * 512);     // proj out
    bf16* bufD  = take((size_t)4096 * 512);     // y1 bf16; bufE (y2 bf16) overlays
    float* R1   = (float*)take((size_t)2 * 4096 * 512);  // y1 fp32
    bf16* bufE  = bufD;                          // y1_bf dead before y2 written
    float* R2   = (float*)x_bf;                  // x_bf/y_bf dead before ln2
    bf16* qcbuf = bufA + (size_t)4096 * 1024;    // kv out uses cols [0,1024)
    if (ws_size < off * sizeof(bf16)) return;    // ws too small: fail loudly (zeros)

    const int NEL = 4096 * 512;
    cvt_f32_bf16<<<NEL / (256 * 8), 256, 0, stream>>>(x, x_bf, NEL);
    cvt_f32_bf16<<<NEL / (256 * 8), 256, 0, stream>>>(y, y_bf, NEL);

    // weight transposes (+ fp32->bf16)
    transpose_w<<<(1536/32)*(512/32), 256, 0, stream>>>(qkv_w, qkv_wT, 512, 1536);
    transpose_w<<<(512/32)*(512/32), 256, 0, stream>>>(self_out_w, self_wT, 512, 512);
    transpose_w<<<(1024/32)*(512/32), 256, 0, stream>>>(kv_w, kv_wT, 512, 1024);
    transpose_w<<<(512/32)*(512/32), 256, 0, stream>>>(q_w, q_wT, 512, 512);
    transpose_w<<<(512/32)*(512/32), 256, 0, stream>>>(cross_out_w, cross_wT, 512, 512);
    transpose_w<<<(2048/32)*(512/32), 256, 0, stream>>>(ffn_w1, ffn1_wT, 512, 2048);
    transpose_w<<<(512/32)*(2048/32), 256, 0, stream>>>(ffn_w2, ffn2_wT, 2048, 512);

    // self-attention branch
    gemm_bt<false><<<(1536/128)*(4096/128), 256, 0, stream>>>(y_bf, qkv_wT, qkv_b, bufA, 4096, 1536, 512);
    attn_simple<<<dim3(32, 16), 256, 0, stream>>>(bufA, bufA + 64, bufA + 128, bufB, 1536, 1536, 192, 192);
    gemm_bt<false><<<(512/128)*(4096/128), 256, 0, stream>>>(bufB, self_wT, self_out_b, bufC, 4096, 512, 512);
    ln_residual<true><<<4096, 64, 0, stream>>>(bufC, y, g1, b1, bufD, R1);

    // cross-attention branch
    gemm_bt<false><<<(1024/128)*(4096/128), 256, 0, stream>>>(x_bf, kv_wT, kv_b, bufA, 4096, 1024, 512);
    gemm_bt<false><<<(512/128)*(4096/128), 256, 0, stream>>>(bufD, q_wT, q_b, qcbuf, 4096, 512, 512);
    attn_simple<<<dim3(32, 16), 256, 0, stream>>>(qcbuf, bufA, bufA + 64, bufB, 512, 1024, 64, 128);
    gemm_bt<false><<<(512/128)*(4096/128), 256, 0, stream>>>(bufB, cross_wT, cross_out_b, bufC, 4096, 512, 512);
    ln_residual<true><<<4096, 64, 0, stream>>>(bufC, R1, g2, b2, bufE, R2);

    // FFN
    gemm_bt<true><<<(2048/128)*(4096/128), 256, 0, stream>>>(bufE, ffn1_wT, ffn_b1, bufA, 4096, 2048, 512);
    gemm_bt<false><<<(512/128)*(4096/128), 256, 0, stream>>>(bufA, ffn2_wT, ffn_b2, bufB, 4096, 512, 2048);
    ln_residual<false><<<4096, 64, 0, stream>>>(bufB, R2, g3, b3, nullptr, (float*)d_out);
}

// Round 6
// 372.849 us; speedup vs baseline: 3.8382x; 3.8382x over previous
//
#include <hip/hip_runtime.h>
#include <hip/hip_bf16.h>
#include <cstdint>
#include <cstddef>

using bf16 = __hip_bfloat16;
typedef __bf16 bf16x8 __attribute__((ext_vector_type(8)));
typedef unsigned short u16x8 __attribute__((ext_vector_type(8)));
typedef float f32x4 __attribute__((ext_vector_type(4)));

__device__ __forceinline__ float bf2f(unsigned short u) {
    union { unsigned int i; float f; } c; c.i = ((unsigned int)u) << 16; return c.f;
}
__device__ __forceinline__ unsigned short f2bf(float f) {
    union { float f; unsigned int i; } c; c.f = f;
    unsigned int r = c.i + 0x7FFFu + ((c.i >> 16) & 1u);
    return (unsigned short)(r >> 16);
}
__device__ __forceinline__ bf16x8 as_bf(u16x8 u) {
    union { u16x8 u; bf16x8 b; } c; c.u = u; return c.b;
}

#define AS1 __attribute__((address_space(1)))
#define AS3 __attribute__((address_space(3)))
__device__ __forceinline__ void gload_lds16(const void* g, void* l) {
    __builtin_amdgcn_global_load_lds((const AS1 void*)g, (AS3 void*)l, 16, 0, 0);
}

// ---------------- fp32 -> bf16 convert (8 elems/thread) -------------------
__global__ __launch_bounds__(256)
void cvt_f32_bf16(const float* __restrict__ in, bf16* __restrict__ out, int n)
{
    const int i = (blockIdx.x * 256 + threadIdx.x) * 8;
    if (i >= n) return;
    float4 a = *(const float4*)(in + i);
    float4 b = *(const float4*)(in + i + 4);
    u16x8 o;
    o[0] = f2bf(a.x); o[1] = f2bf(a.y); o[2] = f2bf(a.z); o[3] = f2bf(a.w);
    o[4] = f2bf(b.x); o[5] = f2bf(b.y); o[6] = f2bf(b.z); o[7] = f2bf(b.w);
    *(u16x8*)((unsigned short*)out + i) = o;
}

// -------- weight transpose + convert: in[K][N] fp32 -> out[N][K] bf16 -----
__global__ __launch_bounds__(256)
void transpose_w(const float* __restrict__ in, bf16* __restrict__ out, int K, int N)
{
    __shared__ unsigned short t[32][33];
    const int nt = N >> 5;
    const int bx = blockIdx.x % nt, by = blockIdx.x / nt;
    const int tx = threadIdx.x & 31, ty = threadIdx.x >> 5;   // ty 0..7
    unsigned short* outu = (unsigned short*)out;
#pragma unroll
    for (int i = 0; i < 32; i += 8)
        t[ty + i][tx] = f2bf(in[(size_t)(by * 32 + ty + i) * N + bx * 32 + tx]);
    __syncthreads();
#pragma unroll
    for (int i = 0; i < 32; i += 8)
        outu[(size_t)(bx * 32 + ty + i) * K + by * 32 + tx] = t[tx][ty + i];
}

// ---------------- GEMM: C[M,N] = A[M,K] @ Bt[N,K]^T + bias, opt ReLU ------
// 128x128 tile, BK=32, 256 threads = 4 waves (2x2), each wave 64x64 out.
// A, Bt bf16; bias fp32; C bf16.  (m97-pattern)
template<bool RELU>
__global__ __launch_bounds__(256)
void gemm_bt(const bf16* __restrict__ A, const bf16* __restrict__ Bt,
             const float* __restrict__ bias, bf16* __restrict__ C,
             int M, int N, int K)
{
    __shared__ unsigned short lA[128 * 32];
    __shared__ unsigned short lB[128 * 32];
    const int tid = threadIdx.x;
    const int lane = tid & 63, wid = tid >> 6;
    const int ntiles = N >> 7;
    const int bx = blockIdx.x % ntiles, by = blockIdx.x / ntiles;
    const long tm = (long)by << 7, tn = (long)bx << 7;

    const int wr = wid >> 1, wc = wid & 1;
    const int lrow = lane & 15, lk8 = (lane >> 4) << 3;

    f32x4 acc[4][4] = {};

    const int srow = wid * 16 + (lane >> 2);
    const int scol = (lane & 3) << 3;
    const bf16* gA0 = A + (tm + srow) * (long)K + scol;
    const bf16* gB0 = Bt + (tn + srow) * (long)K + scol;
    unsigned short* lA0 = lA + (wid * 16) * 32;
    unsigned short* lB0 = lB + (wid * 16) * 32;

    for (int kt = 0; kt < K; kt += 32) {
        gload_lds16(gA0 + kt,                lA0);
        gload_lds16(gA0 + 64 * (long)K + kt, lA0 + 64 * 32);
        gload_lds16(gB0 + kt,                lB0);
        gload_lds16(gB0 + 64 * (long)K + kt, lB0 + 64 * 32);
        __syncthreads();

        bf16x8 af[4], bfv[4];
#pragma unroll
        for (int m = 0; m < 4; ++m)
            af[m] = as_bf(*(const u16x8*)(lA + (wr * 64 + m * 16 + lrow) * 32 + lk8));
#pragma unroll
        for (int n = 0; n < 4; ++n)
            bfv[n] = as_bf(*(const u16x8*)(lB + (wc * 64 + n * 16 + lrow) * 32 + lk8));
#pragma unroll
        for (int m = 0; m < 4; ++m)
#pragma unroll
            for (int n = 0; n < 4; ++n)
                acc[m][n] = __builtin_amdgcn_mfma_f32_16x16x32_bf16(af[m], bfv[n], acc[m][n], 0, 0, 0);
        __syncthreads();
    }

    unsigned short* Cu = (unsigned short*)C;
#pragma unroll
    for (int n = 0; n < 4; ++n) {
        const long gc = tn + wc * 64 + n * 16 + lrow;
        const float bv = bias[gc];
#pragma unroll
        for (int m = 0; m < 4; ++m) {
            const long gr0 = tm + wr * 64 + m * 16 + ((lane >> 4) << 2);
#pragma unroll
            for (int j = 0; j < 4; ++j) {
                float v = acc[m][n][j] + bv;
                if (RELU) v = fmaxf(v, 0.f);
                Cu[(gr0 + j) * (long)N + gc] = f2bf(v);
            }
        }
    }
}

// ---------------- MFMA flash attention ------------------------------------
// grid (S/64, B*H); 256 threads = 4 waves; wave owns 16 q-rows.
// Layouts verified against the green GEMM: A-frag row=lane&15,
// B-frag col=lane&15, D col=lane&15 / row=(lane>>4)*4+j.
__global__ __launch_bounds__(256)
void attn_fwd(const bf16* __restrict__ Qb, const bf16* __restrict__ Kb,
              const bf16* __restrict__ Vb, bf16* __restrict__ Ob,
              int qRS, int kRS, int qHS, int kHS)
{
    __shared__ unsigned short lK[64 * 72];
    __shared__ unsigned short lV[64 * 72];      // transposed: [hd][key]
    __shared__ unsigned short lP[4][16 * 72];

    const int tid = threadIdx.x, lane = tid & 63, wid = tid >> 6;
    const int bh = blockIdx.y, b = bh >> 3, h = bh & 7;
    const int q0 = blockIdx.x * 64 + wid * 16;
    const int lrow = lane & 15, lk8 = (lane >> 4) << 3;

    const unsigned short* Q = (const unsigned short*)Qb + (size_t)b * 2048 * qRS + (size_t)h * qHS;
    const unsigned short* K = (const unsigned short*)Kb + (size_t)b * 2048 * kRS + (size_t)h * kHS;
    const unsigned short* V = (const unsigned short*)Vb + (size_t)b * 2048 * kRS + (size_t)h * kHS;
    unsigned short* O = (unsigned short*)Ob + (size_t)b * 2048 * 512 + (size_t)h * 64;

    // Q fragments, prescaled by 1/sqrt(64)=0.125 (exact in bf16)
    bf16x8 qf[2];
#pragma unroll
    for (int ks = 0; ks < 2; ++ks) {
        u16x8 raw = *(const u16x8*)(Q + (size_t)(q0 + lrow) * qRS + ks * 32 + lk8);
        bf16x8 t;
#pragma unroll
        for (int j = 0; j < 8; ++j) t[j] = (__bf16)(bf2f(raw[j]) * 0.125f);
        qf[ks] = t;
    }

    f32x4 oacc[4] = {};
    float mrow[4], lsum[4];
#pragma unroll
    for (int j = 0; j < 4; ++j) { mrow[j] = -1e30f; lsum[j] = 0.f; }

    const int sr = tid >> 3, sc8 = (tid & 7) << 3;   // 32 rows x 64 cols per pass

    for (int kt = 0; kt < 2048; kt += 64) {
#pragma unroll
        for (int half = 0; half < 64; half += 32) {
            u16x8 k8 = *(const u16x8*)(K + (size_t)(kt + sr + half) * kRS + sc8);
            u16x8 v8 = *(const u16x8*)(V + (size_t)(kt + sr + half) * kRS + sc8);
            *(u16x8*)(lK + (sr + half) * 72 + sc8) = k8;
            // transposed V store; rotate j by sr so the 8 store instructions
            // spread across 8 bank groups instead of 4 (16-way -> 8-way)
#pragma unroll
            for (int jj = 0; jj < 8; ++jj) {
                const int j = (jj + sr) & 7;
                lV[(sc8 + j) * 72 + sr + half] = v8[j];
            }
        }
        __syncthreads();

        f32x4 sf[4] = {};
#pragma unroll
        for (int ks = 0; ks < 2; ++ks)
#pragma unroll
            for (int n = 0; n < 4; ++n) {
                bf16x8 kf = as_bf(*(const u16x8*)(lK + (n * 16 + lrow) * 72 + ks * 32 + lk8));
                sf[n] = __builtin_amdgcn_mfma_f32_16x16x32_bf16(qf[ks], kf, sf[n], 0, 0, 0);
            }

        // online softmax: reg j <-> q-row (lane>>4)*4+j; 16 lanes hold 16 keys/frag
#pragma unroll
        for (int j = 0; j < 4; ++j) {
            float mx = fmaxf(fmaxf(sf[0][j], sf[1][j]), fmaxf(sf[2][j], sf[3][j]));
            mx = fmaxf(mx, __shfl_xor(mx, 1));
            mx = fmaxf(mx, __shfl_xor(mx, 2));
            mx = fmaxf(mx, __shfl_xor(mx, 4));
            mx = fmaxf(mx, __shfl_xor(mx, 8));
            const float nm = fmaxf(mrow[j], mx);
            const float sc = __expf(mrow[j] - nm);
            mrow[j] = nm;
            float rs = 0.f;
#pragma unroll
            for (int n = 0; n < 4; ++n) {
                float p = __expf(sf[n][j] - nm);
                sf[n][j] = p; rs += p;
            }
            rs += __shfl_xor(rs, 1); rs += __shfl_xor(rs, 2);
            rs += __shfl_xor(rs, 4); rs += __shfl_xor(rs, 8);
            lsum[j] = lsum[j] * sc + rs;
#pragma unroll
            for (int n = 0; n < 4; ++n) oacc[n][j] *= sc;
        }

        // P -> per-wave LDS (bf16), layout [qrow][key]
        unsigned short* lPw = lP[wid];
#pragma unroll
        for (int n = 0; n < 4; ++n)
#pragma unroll
            for (int j = 0; j < 4; ++j)
                lPw[(((lane >> 4) << 2) + j) * 72 + n * 16 + lrow] = f2bf(sf[n][j]);

        // order the same-wave cross-lane P write->read (rule-18 class hazard)
        asm volatile("s_waitcnt lgkmcnt(0)" ::: "memory");
        __builtin_amdgcn_sched_barrier(0);

        // PV: O[16x64] += P[16x64] @ V[64x64]
#pragma unroll
        for (int ks = 0; ks < 2; ++ks) {
            bf16x8 pf = as_bf(*(const u16x8*)(lPw + lrow * 72 + ks * 32 + lk8));
#pragma unroll
            for (int n = 0; n < 4; ++n) {
                bf16x8 vf = as_bf(*(const u16x8*)(lV + (n * 16 + lrow) * 72 + ks * 32 + lk8));
                oacc[n] = __builtin_amdgcn_mfma_f32_16x16x32_bf16(pf, vf, oacc[n], 0, 0, 0);
            }
        }
        __syncthreads();
    }

#pragma unroll
    for (int n = 0; n < 4; ++n) {
        const int gc = n * 16 + lrow;
#pragma unroll
        for (int j = 0; j < 4; ++j) {
            float v = oacc[n][j] / lsum[j];
            O[(size_t)(q0 + ((lane >> 4) << 2) + j) * 512 + gc] = f2bf(v);
        }
    }
}

// ------- fused residual + LayerNorm (Bessel, eps on std), fp32 residual ---
// a: bf16 (gemm out); r: fp32 residual; writes fp32 residual-out and
// (optionally) bf16 activation for the next GEMM.
template<bool WRITE_BF>
__global__ __launch_bounds__(64)
void ln_residual(const bf16* __restrict__ a, const float* __restrict__ r,
                 const float* __restrict__ g, const float* __restrict__ bparm,
                 bf16* __restrict__ out_bf, float* __restrict__ out_f32)
{
    const int row = blockIdx.x, lane = threadIdx.x;
    const size_t base = (size_t)row * 512 + lane * 8;
    u16x8 av = *(const u16x8*)((const unsigned short*)a + base);
    float4 rv0 = *(const float4*)(r + base);
    float4 rv1 = *(const float4*)(r + base + 4);
    const float rr[8] = {rv0.x, rv0.y, rv0.z, rv0.w, rv1.x, rv1.y, rv1.z, rv1.w};
    float x[8]; float s = 0.f, ss = 0.f;
#pragma unroll
    for (int j = 0; j < 8; ++j) {
        x[j] = bf2f(av[j]) + rr[j];
        s += x[j]; ss += x[j] * x[j];
    }
#pragma unroll
    for (int off = 32; off > 0; off >>= 1) {
        s += __shfl_xor(s, off);
        ss += __shfl_xor(ss, off);
    }
    const float mean = s * (1.f / 512.f);
    float var = (ss - 512.f * mean * mean) * (1.f / 511.f);
    var = fmaxf(var, 0.f);
    const float inv = 1.f / (sqrtf(var) + 1e-5f);
    float4 gv0 = *(const float4*)(g + lane * 8);
    float4 gv1 = *(const float4*)(g + lane * 8 + 4);
    float4 bv0 = *(const float4*)(bparm + lane * 8);
    float4 bv1 = *(const float4*)(bparm + lane * 8 + 4);
    const float gg[8] = {gv0.x, gv0.y, gv0.z, gv0.w, gv1.x, gv1.y, gv1.z, gv1.w};
    const float bb[8] = {bv0.x, bv0.y, bv0.z, bv0.w, bv1.x, bv1.y, bv1.z, bv1.w};
    float ov[8];
#pragma unroll
    for (int j = 0; j < 8; ++j)
        ov[j] = gg[j] * (x[j] - mean) * inv + bb[j];
    float4 w0 = {ov[0], ov[1], ov[2], ov[3]};
    float4 w1 = {ov[4], ov[5], ov[6], ov[7]};
    *(float4*)(out_f32 + base) = w0;
    *(float4*)(out_f32 + base + 4) = w1;
    if constexpr (WRITE_BF) {
        u16x8 ob;
#pragma unroll
        for (int j = 0; j < 8; ++j) ob[j] = f2bf(ov[j]);
        *(u16x8*)((unsigned short*)out_bf + base) = ob;
    }
}

// ---------------- launch --------------------------------------------------
extern "C" void kernel_launch(void* const* d_in, const int* in_sizes, int n_in,
                              void* d_out, int out_size, void* d_ws, size_t ws_size,
                              hipStream_t stream)
{
    (void)in_sizes; (void)n_in; (void)out_size;
    const float* x          = (const float*)d_in[0];
    const float* y          = (const float*)d_in[1];
    const float* qkv_w      = (const float*)d_in[4];
    const float* qkv_b      = (const float*)d_in[5];
    const float* self_out_w = (const float*)d_in[6];
    const float* self_out_b = (const float*)d_in[7];
    const float* kv_w       = (const float*)d_in[8];
    const float* kv_b       = (const float*)d_in[9];
    const float* q_w        = (const float*)d_in[10];
    const float* q_b        = (const float*)d_in[11];
    const float* cross_out_w= (const float*)d_in[12];
    const float* cross_out_b= (const float*)d_in[13];
    const float* ffn_w1     = (const float*)d_in[14];
    const float* ffn_b1     = (const float*)d_in[15];
    const float* ffn_w2     = (const float*)d_in[16];
    const float* ffn_b2     = (const float*)d_in[17];
    const float* g1 = (const float*)d_in[18];
    const float* b1 = (const float*)d_in[19];
    const float* g2 = (const float*)d_in[20];
    const float* b2 = (const float*)d_in[21];
    const float* g3 = (const float*)d_in[22];
    const float* b3 = (const float*)d_in[23];

    bf16* w = (bf16*)d_ws;
    size_t off = 0;
    auto take = [&](size_t n) { bf16* p = w + off; off += n; return p; };
    bf16* qkv_wT   = take((size_t)1536 * 512);
    bf16* self_wT  = take((size_t)512 * 512);
    bf16* kv_wT    = take((size_t)1024 * 512);
    bf16* q_wT     = take((size_t)512 * 512);
    bf16* cross_wT = take((size_t)512 * 512);
    bf16* ffn1_wT  = take((size_t)2048 * 512);
    bf16* ffn2_wT  = take((size_t)512 * 2048);
    bf16* x_bf  = take((size_t)4096 * 512);     // R2 overlays x_bf+y_bf later
    bf16* y_bf  = take((size_t)4096 * 512);
    bf16* bufA  = take((size_t)4096 * 2048);    // qkv out / kv+q out / ffn1 out
    bf16* bufB  = take((size_t)4096 * 512);     // attn out / ffn2 out
    bf16* bufC  = take((size_t)4096 * 512);     // proj out
    bf16* bufD  = take((size_t)4096 * 512);     // y1 bf16; bufE (y2 bf16) overlays
    float* R1   = (float*)take((size_t)2 * 4096 * 512);  // y1 fp32
    bf16* bufE  = bufD;                          // y1_bf dead before y2 written
    float* R2   = (float*)x_bf;                  // x_bf/y_bf dead before ln2
    bf16* qcbuf = bufA + (size_t)4096 * 1024;    // kv out uses cols [0,1024)
    if (ws_size < off * sizeof(bf16)) return;    // ws too small: fail loudly (zeros)

    const int NEL = 4096 * 512;
    cvt_f32_bf16<<<NEL / (256 * 8), 256, 0, stream>>>(x, x_bf, NEL);
    cvt_f32_bf16<<<NEL / (256 * 8), 256, 0, stream>>>(y, y_bf, NEL);

    // weight transposes (+ fp32->bf16)
    transpose_w<<<(1536/32)*(512/32), 256, 0, stream>>>(qkv_w, qkv_wT, 512, 1536);
    transpose_w<<<(512/32)*(512/32), 256, 0, stream>>>(self_out_w, self_wT, 512, 512);
    transpose_w<<<(1024/32)*(512/32), 256, 0, stream>>>(kv_w, kv_wT, 512, 1024);
    transpose_w<<<(512/32)*(512/32), 256, 0, stream>>>(q_w, q_wT, 512, 512);
    transpose_w<<<(512/32)*(512/32), 256, 0, stream>>>(cross_out_w, cross_wT, 512, 512);
    transpose_w<<<(2048/32)*(512/32), 256, 0, stream>>>(ffn_w1, ffn1_wT, 512, 2048);
    transpose_w<<<(512/32)*(2048/32), 256, 0, stream>>>(ffn_w2, ffn2_wT, 2048, 512);

    // self-attention branch
    gemm_bt<false><<<(1536/128)*(4096/128), 256, 0, stream>>>(y_bf, qkv_wT, qkv_b, bufA, 4096, 1536, 512);
    attn_fwd<<<dim3(32, 16), 256, 0, stream>>>(bufA, bufA + 64, bufA + 128, bufB, 1536, 1536, 192, 192);
    gemm_bt<false><<<(512/128)*(4096/128), 256, 0, stream>>>(bufB, self_wT, self_out_b, bufC, 4096, 512, 512);
    ln_residual<true><<<4096, 64, 0, stream>>>(bufC, y, g1, b1, bufD, R1);

    // cross-attention branch
    gemm_bt<false><<<(1024/128)*(4096/128), 256, 0, stream>>>(x_bf, kv_wT, kv_b, bufA, 4096, 1024, 512);
    gemm_bt<false><<<(512/128)*(4096/128), 256, 0, stream>>>(bufD, q_wT, q_b, qcbuf, 4096, 512, 512);
    attn_fwd<<<dim3(32, 16), 256, 0, stream>>>(qcbuf, bufA, bufA + 64, bufB, 512, 1024, 64, 128);
    gemm_bt<false><<<(512/128)*(4096/128), 256, 0, stream>>>(bufB, cross_wT, cross_out_b, bufC, 4096, 512, 512);
    ln_residual<true><<<4096, 64, 0, stream>>>(bufC, R1, g2, b2, bufE, R2);

    // FFN
    gemm_bt<true><<<(2048/128)*(4096/128), 256, 0, stream>>>(bufE, ffn1_wT, ffn_b1, bufA, 4096, 2048, 512);
    gemm_bt<false><<<(512/128)*(4096/128), 256, 0, stream>>>(bufA, ffn2_wT, ffn_b2, bufB, 4096, 512, 2048);
    ln_residual<false><<<4096, 64, 0, stream>>>(bufB, R2, g3, b3, nullptr, (float*)d_out);
}